// Round 2
// baseline (176.967 us; speedup 1.0000x reference)
//
#include <hip/hip_runtime.h>

#define D 64
#define K 400
#define KT 25            // K/16 code tiles
#define BLOCK 1024
#define WPB (BLOCK / 64) // 16 waves per block

typedef _Float16 f16x8 __attribute__((ext_vector_type(8)));
typedef float f32x4 __attribute__((ext_vector_type(4)));

// scores = ||e||^2 - 2 x.e ; computed via f16 hi/lo split MFMA:
//   2e = eh + 2^-11 el,  x = xh + 2^-11 xl   (el, xl stored pre-scaled by 2^11)
//   dot(x,2e) ~= [xh.eh] + 2^-11 [xh.el + xl.eh]
// argmax over (dot - ||e||^2)  ==  argmin over score.
__global__ __launch_bounds__(BLOCK, 4) void vq_mfma(
    const float* __restrict__ x,
    const float* __restrict__ emb,
    float* __restrict__ out,
    int nrows) {
  // B frags in MFMA lane order: [tile][frag {c0hi,c0lo,c1hi,c1lo}][lane][8]
  __shared__ __align__(16) _Float16 sB[KT][4][64][8]; // 102,400 B
  __shared__ float s_norm[K];                         // 1,600 B

  const int tid = threadIdx.x;

  // ---- stage codebook into fragment-ordered LDS ----
  for (int e = tid; e < KT * 4 * 64; e += BLOCK) {
    int t = e >> 8;
    int f = (e >> 6) & 3;
    int l = e & 63;
    int code = t * 16 + (l & 15);
    int kb = ((l >> 4) << 3) + ((f >> 1) << 5);
    const float* ep = emb + code * D + kb;
    float v[8];
    *(float4*)&v[0] = *(const float4*)ep;
    *(float4*)&v[4] = *(const float4*)(ep + 4);
    _Float16 h[8];
    if ((f & 1) == 0) {
#pragma unroll
      for (int j = 0; j < 8; ++j) h[j] = (_Float16)(2.0f * v[j]);
    } else {
#pragma unroll
      for (int j = 0; j < 8; ++j) {
        float s = 2.0f * v[j];
        _Float16 hh = (_Float16)s;
        float r = s - (float)hh;
        h[j] = (_Float16)(r * 2048.0f); // scaled 2^11: stays normal f16
      }
    }
    *(f16x8*)&sB[t][f][l][0] = *(f16x8*)&h[0];
  }
  for (int k = tid; k < K; k += BLOCK) {
    const float4* ep = (const float4*)(emb + (size_t)k * D);
    float4 s4 = {0.f, 0.f, 0.f, 0.f};
#pragma unroll
    for (int d = 0; d < 16; ++d) {
      float4 v = ep[d];
      s4.x = fmaf(v.x, v.x, s4.x);
      s4.y = fmaf(v.y, v.y, s4.y);
      s4.z = fmaf(v.z, v.z, s4.z);
      s4.w = fmaf(v.w, v.w, s4.w);
    }
    s_norm[k] = (s4.x + s4.y) + (s4.z + s4.w);
  }
  __syncthreads();

  const int lane = tid & 63;
  const int wid = tid >> 6;
  const int gw = blockIdx.x * WPB + wid;
  const int nw = gridDim.x * WPB;
  const int l15 = lane & 15;
  const int q = lane >> 4;

  const f32x4 zq = {0.f, 0.f, 0.f, 0.f}; // reusable C-operand: no per-tile init movs

// LOADB prefetches the NEXT tile's B-fragments + norm; the sched_barrier
// after each call pins the ds_reads a full tile ahead of their use.
#define LOADB(Bf, Nf, T)                           \
  do {                                             \
    Bf##0 = *(const f16x8*)&sB[(T)][0][lane][0];   \
    Bf##1 = *(const f16x8*)&sB[(T)][1][lane][0];   \
    Bf##2 = *(const f16x8*)&sB[(T)][2][lane][0];   \
    Bf##3 = *(const f16x8*)&sB[(T)][3][lane][0];   \
    Nf = s_norm[(T) * 16 + l15];                   \
    __builtin_amdgcn_sched_barrier(0);             \
  } while (0)

#define PROC(Bf, Nf, T)                                                        \
  do {                                                                         \
    _Pragma("unroll") for (int a_ = 0; a_ < 2; ++a_) {                         \
      f32x4 ah, al;                                                            \
      __builtin_amdgcn_s_setprio(1);                                           \
      ah = __builtin_amdgcn_mfma_f32_16x16x32_f16(xh[a_][0], Bf##0, zq, 0, 0, 0); \
      ah = __builtin_amdgcn_mfma_f32_16x16x32_f16(xh[a_][1], Bf##2, ah, 0, 0, 0); \
      al = __builtin_amdgcn_mfma_f32_16x16x32_f16(xh[a_][0], Bf##1, zq, 0, 0, 0); \
      al = __builtin_amdgcn_mfma_f32_16x16x32_f16(xl[a_][0], Bf##0, al, 0, 0, 0); \
      al = __builtin_amdgcn_mfma_f32_16x16x32_f16(xh[a_][1], Bf##3, al, 0, 0, 0); \
      al = __builtin_amdgcn_mfma_f32_16x16x32_f16(xl[a_][1], Bf##2, al, 0, 0, 0); \
      __builtin_amdgcn_s_setprio(0);                                           \
      _Pragma("unroll") for (int i_ = 0; i_ < 4; ++i_) {                       \
        float m_ = fmaf(al[i_], 4.8828125e-4f, ah[i_]) - (Nf);                 \
        bool gt_ = m_ > bestm[a_][i_];                                         \
        bestm[a_][i_] = gt_ ? m_ : bestm[a_][i_];                              \
        bestt[a_][i_] = gt_ ? (T) : bestt[a_][i_];                             \
      }                                                                        \
    }                                                                          \
  } while (0)

  const int npair = nrows >> 5; // 32 rows per wave-iteration

  // raw next-pair A data, prefetched a full pair-iteration ahead
  float4 pv[2][2][2];
  int p0 = gw;
  if (p0 < npair) {
#pragma unroll
    for (int a = 0; a < 2; ++a)
#pragma unroll
      for (int c = 0; c < 2; ++c) {
        const float* xp =
            x + (size_t)((p0 << 5) + a * 16 + l15) * D + q * 8 + c * 32;
        pv[a][c][0] = *(const float4*)xp;
        pv[a][c][1] = *(const float4*)(xp + 4);
      }
  }

  for (int p = gw; p < npair; p += nw) {
    const int row0 = p << 5;

    // ---- split prefetched A into hi/lo fragments (regs only) ----
    f16x8 xh[2][2], xl[2][2];
#pragma unroll
    for (int a = 0; a < 2; ++a)
#pragma unroll
      for (int c = 0; c < 2; ++c) {
        float v[8];
        *(float4*)&v[0] = pv[a][c][0];
        *(float4*)&v[4] = pv[a][c][1];
        _Float16 hh[8], ll[8];
#pragma unroll
        for (int j = 0; j < 8; ++j) {
          _Float16 h = (_Float16)v[j];
          float r = v[j] - (float)h;
          hh[j] = h;
          ll[j] = (_Float16)(r * 2048.0f);
        }
        xh[a][c] = *(f16x8*)&hh[0];
        xl[a][c] = *(f16x8*)&ll[0];
      }

    // ---- issue next pair's loads; latency hides under the 25-tile loop ----
    {
      int pn = p + nw;
      if (pn < npair) {
#pragma unroll
        for (int a = 0; a < 2; ++a)
#pragma unroll
          for (int c = 0; c < 2; ++c) {
            const float* xp =
                x + (size_t)((pn << 5) + a * 16 + l15) * D + q * 8 + c * 32;
            pv[a][c][0] = *(const float4*)xp;
            pv[a][c][1] = *(const float4*)(xp + 4);
          }
        __builtin_amdgcn_sched_barrier(0); // keep loads issued here, not sunk
      }
    }

    float bestm[2][4];
    int bestt[2][4];
#pragma unroll
    for (int a = 0; a < 2; ++a)
#pragma unroll
      for (int i = 0; i < 4; ++i) {
        bestm[a][i] = -3.4e38f;
        bestt[a][i] = 0;
      }

    // ---- 25 code tiles, 2-deep pipeline (even/odd reg sets, pinned) ----
    f16x8 bA0, bA1, bA2, bA3, bB0, bB1, bB2, bB3;
    float nA, nB;
    LOADB(bA, nA, 0);
    for (int t2 = 0; t2 < 12; ++t2) {
      LOADB(bB, nB, 2 * t2 + 1);
      PROC(bA, nA, 2 * t2);
      LOADB(bA, nA, 2 * t2 + 2);
      PROC(bB, nB, 2 * t2 + 1);
    }
    PROC(bA, nA, 24);

    // ---- argmin reduce: both a-chains interleaved to overlap shfl latency ----
    float bv[2][4];
    int bk[2][4];
#pragma unroll
    for (int a = 0; a < 2; ++a)
#pragma unroll
      for (int i = 0; i < 4; ++i) {
        bv[a][i] = bestm[a][i];
        bk[a][i] = bestt[a][i] * 16 + l15;
      }
#pragma unroll
    for (int m = 1; m <= 8; m <<= 1) {
#pragma unroll
      for (int a = 0; a < 2; ++a)
#pragma unroll
        for (int i = 0; i < 4; ++i) {
          float ov = __shfl_xor(bv[a][i], m, 64);
          int ok = __shfl_xor(bk[a][i], m, 64);
          bool take = (ov > bv[a][i]) || ((ov == bv[a][i]) && (ok < bk[a][i]));
          bv[a][i] = take ? ov : bv[a][i];
          bk[a][i] = take ? ok : bk[a][i];
        }
    }
#pragma unroll
    for (int a = 0; a < 2; ++a) {
      // row r = row0+a*16+(lane>>2); its group (lane>>4) holds that row's bk
      int j = (lane >> 2) & 3;
      int k01 = (j & 1) ? bk[a][1] : bk[a][0];
      int k23 = (j & 1) ? bk[a][3] : bk[a][2];
      int kk = (j & 2) ? k23 : k01;
      int r = row0 + a * 16 + (lane >> 2);
      // coalesced: store inst s covers full 64B segments (4 lanes x 16B)
      const f32x4* src = (const f32x4*)(emb + (size_t)kk * D);
      f32x4* dst = (f32x4*)(out + (size_t)r * D);
#pragma unroll
      for (int s = 0; s < 4; ++s) {
        int idx = (lane & 3) + (s << 2);
        dst[idx] = src[idx];
      }
    }
  }
#undef LOADB
#undef PROC
}

extern "C" void kernel_launch(void* const* d_in, const int* in_sizes, int n_in,
                              void* d_out, int out_size, void* d_ws, size_t ws_size,
                              hipStream_t stream) {
  const float* x = (const float*)d_in[0];
  const float* emb = (const float*)d_in[1];
  float* out = (float*)d_out;
  int nrows = in_sizes[0] / D; // 262144
  vq_mfma<<<256, BLOCK, 0, stream>>>(x, emb, out, nrows);
}

// Round 3
// 175.339 us; speedup vs baseline: 1.0093x; 1.0093x over previous
//
#include <hip/hip_runtime.h>

#define D 64
#define K 400
#define KT 25            // K/16 code tiles
#define BLOCK 1024
#define WPB (BLOCK / 64) // 16 waves per block

typedef _Float16 f16x8 __attribute__((ext_vector_type(8)));
typedef float f32x4 __attribute__((ext_vector_type(4)));

// scores = ||e||^2 - 2 x.e ; computed via f16 hi/lo split MFMA:
//   2e = eh + 2^-11 el,  x = xh + 2^-11 xl   (el, xl stored pre-scaled by 2^11)
//   dot(x,2e) ~= [xh.eh] + 2^-11 [xh.el + xl.eh]
// argmax over (dot - ||e||^2)  ==  argmin over score.
// -||e||^2 is folded into the hi-accumulator init.
//
// R3 structure: 64 rows per wave (a=0..3), exactly ONE iteration per wave
// (4096 waves x 64 rows = 262144). 24 MFMAs per 4 ds_read_b128 -> tile t's
// MFMA issue (~470cy) covers tile t+1's LDS latency; no manual pipelining.
// No local float arrays (R2's PromoteAlloca->LDS pathology), no sched pins.

#define SPL(hh, ll, j, val)                          \
  do {                                               \
    float v_ = (val);                                \
    _Float16 t_ = (_Float16)v_;                      \
    (hh)[j] = t_;                                    \
    (ll)[j] = (_Float16)((v_ - (float)t_) * 2048.0f);\
  } while (0)

__global__ __launch_bounds__(BLOCK, 4) void vq_mfma(
    const float* __restrict__ x,
    const float* __restrict__ emb,
    float* __restrict__ out,
    int nrows) {
  // B frags in MFMA lane order: [tile][frag {c0hi,c0lo,c1hi,c1lo}][lane][8]
  __shared__ __align__(16) _Float16 sB[KT][4][64][8]; // 102,400 B
  __shared__ float s_norm[K];                         // 1,600 B

  const int tid = threadIdx.x;

  // ---- stage codebook into fragment-ordered LDS ----
  for (int e = tid; e < KT * 4 * 64; e += BLOCK) {
    int t = e >> 8;
    int f = (e >> 6) & 3;
    int l = e & 63;
    int code = t * 16 + (l & 15);
    int kb = ((l >> 4) << 3) + ((f >> 1) << 5);
    const float* ep = emb + code * D + kb;
    float4 u = *(const float4*)ep;
    float4 w = *(const float4*)(ep + 4);
    f16x8 h;
    if ((f & 1) == 0) {
      h[0] = (_Float16)(2.0f * u.x);
      h[1] = (_Float16)(2.0f * u.y);
      h[2] = (_Float16)(2.0f * u.z);
      h[3] = (_Float16)(2.0f * u.w);
      h[4] = (_Float16)(2.0f * w.x);
      h[5] = (_Float16)(2.0f * w.y);
      h[6] = (_Float16)(2.0f * w.z);
      h[7] = (_Float16)(2.0f * w.w);
    } else {
#define LOC(j, val)                                    \
      do {                                             \
        float s_ = 2.0f * (val);                       \
        _Float16 t_ = (_Float16)s_;                    \
        h[j] = (_Float16)((s_ - (float)t_) * 2048.0f); \
      } while (0)
      LOC(0, u.x); LOC(1, u.y); LOC(2, u.z); LOC(3, u.w);
      LOC(4, w.x); LOC(5, w.y); LOC(6, w.z); LOC(7, w.w);
#undef LOC
    }
    *(f16x8*)&sB[t][f][l][0] = h;
  }
  for (int k = tid; k < K; k += BLOCK) {
    const float4* ep = (const float4*)(emb + (size_t)k * D);
    float4 s4 = {0.f, 0.f, 0.f, 0.f};
#pragma unroll
    for (int d = 0; d < 16; ++d) {
      float4 v = ep[d];
      s4.x = fmaf(v.x, v.x, s4.x);
      s4.y = fmaf(v.y, v.y, s4.y);
      s4.z = fmaf(v.z, v.z, s4.z);
      s4.w = fmaf(v.w, v.w, s4.w);
    }
    s_norm[k] = (s4.x + s4.y) + (s4.z + s4.w);
  }
  __syncthreads();

  const int lane = tid & 63;
  const int wid = tid >> 6;
  const int gw = blockIdx.x * WPB + wid;
  const int nw = gridDim.x * WPB;
  const int l15 = lane & 15;
  const int q = lane >> 4;

  const int ngrp = nrows >> 6; // 64 rows per wave-iteration
  for (int g = gw; g < ngrp; g += nw) {
    const int row0 = g << 6;

    // ---- load + split A fragments (64 rows x 2 k-halves, regs only) ----
    f16x8 xh[4][2], xl[4][2];
#pragma unroll
    for (int a = 0; a < 4; ++a)
#pragma unroll
      for (int c = 0; c < 2; ++c) {
        const float* xp =
            x + (size_t)(row0 + a * 16 + l15) * D + q * 8 + c * 32;
        float4 u = *(const float4*)xp;
        float4 w = *(const float4*)(xp + 4);
        f16x8 hh, ll;
        SPL(hh, ll, 0, u.x);
        SPL(hh, ll, 1, u.y);
        SPL(hh, ll, 2, u.z);
        SPL(hh, ll, 3, u.w);
        SPL(hh, ll, 4, w.x);
        SPL(hh, ll, 5, w.y);
        SPL(hh, ll, 6, w.z);
        SPL(hh, ll, 7, w.w);
        xh[a][c] = hh;
        xl[a][c] = ll;
      }

    float bestm[4][4];
    int bestt[4][4];
#pragma unroll
    for (int a = 0; a < 4; ++a)
#pragma unroll
      for (int i = 0; i < 4; ++i) {
        bestm[a][i] = -3.4e38f;
        bestt[a][i] = 0;
      }

    // ---- 25 code tiles: 4 ds_read_b128 feed 24 MFMAs ----
    for (int t = 0; t < KT; ++t) {
      f16x8 b0 = *(const f16x8*)&sB[t][0][lane][0];
      f16x8 b1 = *(const f16x8*)&sB[t][1][lane][0];
      f16x8 b2 = *(const f16x8*)&sB[t][2][lane][0];
      f16x8 b3 = *(const f16x8*)&sB[t][3][lane][0];
      float nn = -s_norm[t * 16 + l15];
#pragma unroll
      for (int a = 0; a < 4; ++a) {
        f32x4 ah = {nn, nn, nn, nn};
        f32x4 al = {0.f, 0.f, 0.f, 0.f};
        ah = __builtin_amdgcn_mfma_f32_16x16x32_f16(xh[a][0], b0, ah, 0, 0, 0);
        ah = __builtin_amdgcn_mfma_f32_16x16x32_f16(xh[a][1], b2, ah, 0, 0, 0);
        al = __builtin_amdgcn_mfma_f32_16x16x32_f16(xh[a][0], b1, al, 0, 0, 0);
        al = __builtin_amdgcn_mfma_f32_16x16x32_f16(xl[a][0], b0, al, 0, 0, 0);
        al = __builtin_amdgcn_mfma_f32_16x16x32_f16(xh[a][1], b3, al, 0, 0, 0);
        al = __builtin_amdgcn_mfma_f32_16x16x32_f16(xl[a][1], b2, al, 0, 0, 0);
#pragma unroll
        for (int i = 0; i < 4; ++i) {
          float m = fmaf(al[i], 4.8828125e-4f, ah[i]); // includes -||e||^2
          bool gt = m > bestm[a][i];
          bestm[a][i] = gt ? m : bestm[a][i];
          bestt[a][i] = gt ? t : bestt[a][i];
        }
      }
    }

    // ---- argmin reduce: all 4 a-chains interleaved (overlap shfl latency) ----
    float bv[4][4];
    int bk[4][4];
#pragma unroll
    for (int a = 0; a < 4; ++a)
#pragma unroll
      for (int i = 0; i < 4; ++i) {
        bv[a][i] = bestm[a][i];
        bk[a][i] = bestt[a][i] * 16 + l15;
      }
#pragma unroll
    for (int m = 1; m <= 8; m <<= 1) {
#pragma unroll
      for (int a = 0; a < 4; ++a)
#pragma unroll
        for (int i = 0; i < 4; ++i) {
          float ov = __shfl_xor(bv[a][i], m, 64);
          int ok = __shfl_xor(bk[a][i], m, 64);
          bool take = (ov > bv[a][i]) || ((ov == bv[a][i]) && (ok < bk[a][i]));
          bv[a][i] = take ? ov : bv[a][i];
          bk[a][i] = take ? ok : bk[a][i];
        }
    }
#pragma unroll
    for (int a = 0; a < 4; ++a) {
      // row r = row0+a*16+(lane>>2); its group (lane>>4) holds that row's bk
      int j = (lane >> 2) & 3;
      int k01 = (j & 1) ? bk[a][1] : bk[a][0];
      int k23 = (j & 1) ? bk[a][3] : bk[a][2];
      int kk = (j & 2) ? k23 : k01;
      int r = row0 + a * 16 + (lane >> 2);
      // each store inst: 4-lane groups cover full 64B row segments
      const f32x4* src = (const f32x4*)(emb + (size_t)kk * D);
      f32x4* dst = (f32x4*)(out + (size_t)r * D);
#pragma unroll
      for (int s = 0; s < 4; ++s) {
        int idx = (lane & 3) + (s << 2);
        dst[idx] = src[idx];
      }
    }
  }
}

extern "C" void kernel_launch(void* const* d_in, const int* in_sizes, int n_in,
                              void* d_out, int out_size, void* d_ws, size_t ws_size,
                              hipStream_t stream) {
  const float* x = (const float*)d_in[0];
  const float* emb = (const float*)d_in[1];
  float* out = (float*)d_out;
  int nrows = in_sizes[0] / D; // 262144
  vq_mfma<<<256, BLOCK, 0, stream>>>(x, emb, out, nrows);
}

// Round 4
// 172.055 us; speedup vs baseline: 1.0285x; 1.0191x over previous
//
#include <hip/hip_runtime.h>

#define D 64
#define K 400
#define KT 25           // K/16 code tiles
#define BLOCK 512
#define WPB (BLOCK / 64) // 8 waves per block

typedef _Float16 f16x8 __attribute__((ext_vector_type(8)));
typedef float f32x4 __attribute__((ext_vector_type(4)));

// scores = ||e||^2 - 2 x.e ; computed via f16 hi/lo split MFMA:
//   2e = eh + 2^-11 el,  x = xh + 2^-11 xl   (el, xl stored pre-scaled by 2^11)
//   dot(x,2e) ~= [xh.eh] + 2^-11 [xh.el + xl.eh]
// argmax over (dot - ||e||^2)  ==  argmin over score.
// -||e||^2 is folded into the hi-accumulator init.
//
// R4: a=4 (64 rows/wave, 24 MFMAs per 4 ds_read_b128) with BLOCK=512 and
// __launch_bounds__(512,2): LDS (104KB) pins 1 block/CU either way, so the
// smaller block lifts the per-wave VGPR cap to 256 and the a=4 state
// (~140 regs) lives in registers instead of spilling (R3: VGPR=64 + 55MB
// scratch traffic). 2 waves/SIMD, compensated by 4x within-wave ILP.

#define SPL(hh, ll, j, val)                          \
  do {                                               \
    float v_ = (val);                                \
    _Float16 t_ = (_Float16)v_;                      \
    (hh)[j] = t_;                                    \
    (ll)[j] = (_Float16)((v_ - (float)t_) * 2048.0f);\
  } while (0)

__global__ __launch_bounds__(BLOCK, 2) void vq_mfma(
    const float* __restrict__ x,
    const float* __restrict__ emb,
    float* __restrict__ out,
    int nrows) {
  // B frags in MFMA lane order: [tile][frag {c0hi,c0lo,c1hi,c1lo}][lane][8]
  __shared__ __align__(16) _Float16 sB[KT][4][64][8]; // 102,400 B
  __shared__ float s_norm[K];                         // 1,600 B

  const int tid = threadIdx.x;

  // ---- stage codebook into fragment-ordered LDS ----
  for (int e = tid; e < KT * 4 * 64; e += BLOCK) {
    int t = e >> 8;
    int f = (e >> 6) & 3;
    int l = e & 63;
    int code = t * 16 + (l & 15);
    int kb = ((l >> 4) << 3) + ((f >> 1) << 5);
    const float* ep = emb + code * D + kb;
    float4 u = *(const float4*)ep;
    float4 w = *(const float4*)(ep + 4);
    f16x8 h;
    if ((f & 1) == 0) {
      h[0] = (_Float16)(2.0f * u.x);
      h[1] = (_Float16)(2.0f * u.y);
      h[2] = (_Float16)(2.0f * u.z);
      h[3] = (_Float16)(2.0f * u.w);
      h[4] = (_Float16)(2.0f * w.x);
      h[5] = (_Float16)(2.0f * w.y);
      h[6] = (_Float16)(2.0f * w.z);
      h[7] = (_Float16)(2.0f * w.w);
    } else {
#define LOC(j, val)                                    \
      do {                                             \
        float s_ = 2.0f * (val);                       \
        _Float16 t_ = (_Float16)s_;                    \
        h[j] = (_Float16)((s_ - (float)t_) * 2048.0f); \
      } while (0)
      LOC(0, u.x); LOC(1, u.y); LOC(2, u.z); LOC(3, u.w);
      LOC(4, w.x); LOC(5, w.y); LOC(6, w.z); LOC(7, w.w);
#undef LOC
    }
    *(f16x8*)&sB[t][f][l][0] = h;
  }
  for (int k = tid; k < K; k += BLOCK) {
    const float4* ep = (const float4*)(emb + (size_t)k * D);
    float4 s4 = {0.f, 0.f, 0.f, 0.f};
#pragma unroll
    for (int d = 0; d < 16; ++d) {
      float4 v = ep[d];
      s4.x = fmaf(v.x, v.x, s4.x);
      s4.y = fmaf(v.y, v.y, s4.y);
      s4.z = fmaf(v.z, v.z, s4.z);
      s4.w = fmaf(v.w, v.w, s4.w);
    }
    s_norm[k] = (s4.x + s4.y) + (s4.z + s4.w);
  }
  __syncthreads();

  const int lane = tid & 63;
  const int wid = tid >> 6;
  const int gw = blockIdx.x * WPB + wid;
  const int nw = gridDim.x * WPB;
  const int l15 = lane & 15;
  const int q = lane >> 4;

  const int ngrp = nrows >> 6; // 64 rows per wave-iteration
  for (int g = gw; g < ngrp; g += nw) {
    const int row0 = g << 6;

    // ---- load + split A fragments (64 rows x 2 k-halves, regs only) ----
    f16x8 xh[4][2], xl[4][2];
#pragma unroll
    for (int a = 0; a < 4; ++a) {
      const float* xp = x + (size_t)(row0 + a * 16 + l15) * D + q * 8;
      // issue all 4 loads for this row-tile before converting
      float4 u0 = *(const float4*)xp;
      float4 u1 = *(const float4*)(xp + 4);
      float4 w0 = *(const float4*)(xp + 32);
      float4 w1 = *(const float4*)(xp + 36);
      f16x8 hh0, ll0, hh1, ll1;
      SPL(hh0, ll0, 0, u0.x); SPL(hh0, ll0, 1, u0.y);
      SPL(hh0, ll0, 2, u0.z); SPL(hh0, ll0, 3, u0.w);
      SPL(hh0, ll0, 4, u1.x); SPL(hh0, ll0, 5, u1.y);
      SPL(hh0, ll0, 6, u1.z); SPL(hh0, ll0, 7, u1.w);
      SPL(hh1, ll1, 0, w0.x); SPL(hh1, ll1, 1, w0.y);
      SPL(hh1, ll1, 2, w0.z); SPL(hh1, ll1, 3, w0.w);
      SPL(hh1, ll1, 4, w1.x); SPL(hh1, ll1, 5, w1.y);
      SPL(hh1, ll1, 6, w1.z); SPL(hh1, ll1, 7, w1.w);
      xh[a][0] = hh0; xl[a][0] = ll0;
      xh[a][1] = hh1; xl[a][1] = ll1;
    }

    float bestm[4][4];
    int bestt[4][4];
#pragma unroll
    for (int a = 0; a < 4; ++a)
#pragma unroll
      for (int i = 0; i < 4; ++i) {
        bestm[a][i] = -3.4e38f;
        bestt[a][i] = 0;
      }

    // ---- 25 code tiles: 4 ds_read_b128 feed 24 MFMAs ----
    for (int t = 0; t < KT; ++t) {
      f16x8 b0 = *(const f16x8*)&sB[t][0][lane][0];
      f16x8 b1 = *(const f16x8*)&sB[t][1][lane][0];
      f16x8 b2 = *(const f16x8*)&sB[t][2][lane][0];
      f16x8 b3 = *(const f16x8*)&sB[t][3][lane][0];
      float nn = -s_norm[t * 16 + l15];
#pragma unroll
      for (int a = 0; a < 4; ++a) {
        f32x4 ah = {nn, nn, nn, nn};
        f32x4 al = {0.f, 0.f, 0.f, 0.f};
        ah = __builtin_amdgcn_mfma_f32_16x16x32_f16(xh[a][0], b0, ah, 0, 0, 0);
        ah = __builtin_amdgcn_mfma_f32_16x16x32_f16(xh[a][1], b2, ah, 0, 0, 0);
        al = __builtin_amdgcn_mfma_f32_16x16x32_f16(xh[a][0], b1, al, 0, 0, 0);
        al = __builtin_amdgcn_mfma_f32_16x16x32_f16(xl[a][0], b0, al, 0, 0, 0);
        al = __builtin_amdgcn_mfma_f32_16x16x32_f16(xh[a][1], b3, al, 0, 0, 0);
        al = __builtin_amdgcn_mfma_f32_16x16x32_f16(xl[a][1], b2, al, 0, 0, 0);
#pragma unroll
        for (int i = 0; i < 4; ++i) {
          float m = fmaf(al[i], 4.8828125e-4f, ah[i]); // includes -||e||^2
          bool gt = m > bestm[a][i];
          bestm[a][i] = gt ? m : bestm[a][i];
          bestt[a][i] = gt ? t : bestt[a][i];
        }
      }
    }

    // ---- argmin reduce: all 4 a-chains interleaved (overlap shfl latency) ----
    float bv[4][4];
    int bk[4][4];
#pragma unroll
    for (int a = 0; a < 4; ++a)
#pragma unroll
      for (int i = 0; i < 4; ++i) {
        bv[a][i] = bestm[a][i];
        bk[a][i] = bestt[a][i] * 16 + l15;
      }
#pragma unroll
    for (int m = 1; m <= 8; m <<= 1) {
#pragma unroll
      for (int a = 0; a < 4; ++a)
#pragma unroll
        for (int i = 0; i < 4; ++i) {
          float ov = __shfl_xor(bv[a][i], m, 64);
          int ok = __shfl_xor(bk[a][i], m, 64);
          bool take = (ov > bv[a][i]) || ((ov == bv[a][i]) && (ok < bk[a][i]));
          bv[a][i] = take ? ov : bv[a][i];
          bk[a][i] = take ? ok : bk[a][i];
        }
    }
#pragma unroll
    for (int a = 0; a < 4; ++a) {
      // row r = row0+a*16+(lane>>2); its group (lane>>4) holds that row's bk
      int j = (lane >> 2) & 3;
      int k01 = (j & 1) ? bk[a][1] : bk[a][0];
      int k23 = (j & 1) ? bk[a][3] : bk[a][2];
      int kk = (j & 2) ? k23 : k01;
      int r = row0 + a * 16 + (lane >> 2);
      // each store inst: 4-lane groups cover full 64B row segments
      const f32x4* src = (const f32x4*)(emb + (size_t)kk * D);
      f32x4* dst = (f32x4*)(out + (size_t)r * D);
#pragma unroll
      for (int s = 0; s < 4; ++s) {
        int idx = (lane & 3) + (s << 2);
        dst[idx] = src[idx];
      }
    }
  }
}

extern "C" void kernel_launch(void* const* d_in, const int* in_sizes, int n_in,
                              void* d_out, int out_size, void* d_ws, size_t ws_size,
                              hipStream_t stream) {
  const float* x = (const float*)d_in[0];
  const float* emb = (const float*)d_in[1];
  float* out = (float*)d_out;
  int nrows = in_sizes[0] / D; // 262144
  vq_mfma<<<512, BLOCK, 0, stream>>>(x, emb, out, nrows);
}

// Round 5
// 162.460 us; speedup vs baseline: 1.0893x; 1.0591x over previous
//
#include <hip/hip_runtime.h>

#define D 64
#define K 400
#define KT 25            // K/16 code tiles
#define BLOCK 512
#define WPB (BLOCK / 64) // 8 waves per block

typedef _Float16 f16x8 __attribute__((ext_vector_type(8)));
typedef float f32x4 __attribute__((ext_vector_type(4)));
typedef int i32x4 __attribute__((ext_vector_type(4)));

// scores = ||e||^2 - 2 x.e ; computed via f16 hi/lo split MFMA:
//   2e = eh + 2^-11 el,  x = xh + 2^-11 xl   (el, xl stored pre-scaled by 2^11)
//   dot(x,2e) ~= [xh.eh] + 2^-11 [xh.el + xl.eh]
// argmax over (dot - ||e||^2)  ==  argmin over score.
//
// R5: R4's a=4 structure (64 rows/wave, 24 MFMAs per 4 ds_read_b128,
// BLOCK=512, launch_bounds(512,2)) with ZERO allocas: all per-thread state
// is named ext_vector SSA variables. R2/R3/R4 showed every local C array
// either spills to scratch (R3: +55MB traffic) or gets PromoteAlloca'd
// into LDS (R2/R4: +32KB LDS, 5.2M bank conflicts). Vector subscripts
// lower to insert/extract-element -- nothing for PromoteAlloca to grab.

#define SPL(hh, ll, j, val)                          \
  do {                                               \
    float v_ = (val);                                \
    _Float16 t_ = (_Float16)v_;                      \
    (hh)[j] = t_;                                    \
    (ll)[j] = (_Float16)((v_ - (float)t_) * 2048.0f);\
  } while (0)

__global__ __launch_bounds__(BLOCK, 2) void vq_mfma(
    const float* __restrict__ x,
    const float* __restrict__ emb,
    float* __restrict__ out,
    int nrows) {
  // B frags in MFMA lane order: [tile][frag {c0hi,c0lo,c1hi,c1lo}][lane][8]
  __shared__ __align__(16) _Float16 sB[KT][4][64][8]; // 102,400 B
  __shared__ float s_norm[K];                         // 1,600 B

  const int tid = threadIdx.x;

  // ---- stage codebook into fragment-ordered LDS ----
  for (int e = tid; e < KT * 4 * 64; e += BLOCK) {
    int t = e >> 8;
    int f = (e >> 6) & 3;
    int l = e & 63;
    int code = t * 16 + (l & 15);
    int kb = ((l >> 4) << 3) + ((f >> 1) << 5);
    const float* ep = emb + code * D + kb;
    float4 u = *(const float4*)ep;
    float4 w = *(const float4*)(ep + 4);
    f16x8 h;
    if ((f & 1) == 0) {
      h[0] = (_Float16)(2.0f * u.x);
      h[1] = (_Float16)(2.0f * u.y);
      h[2] = (_Float16)(2.0f * u.z);
      h[3] = (_Float16)(2.0f * u.w);
      h[4] = (_Float16)(2.0f * w.x);
      h[5] = (_Float16)(2.0f * w.y);
      h[6] = (_Float16)(2.0f * w.z);
      h[7] = (_Float16)(2.0f * w.w);
    } else {
#define LOC(j, val)                                    \
      do {                                             \
        float s_ = 2.0f * (val);                       \
        _Float16 t_ = (_Float16)s_;                    \
        h[j] = (_Float16)((s_ - (float)t_) * 2048.0f); \
      } while (0)
      LOC(0, u.x); LOC(1, u.y); LOC(2, u.z); LOC(3, u.w);
      LOC(4, w.x); LOC(5, w.y); LOC(6, w.z); LOC(7, w.w);
#undef LOC
    }
    *(f16x8*)&sB[t][f][l][0] = h;
  }
  for (int k = tid; k < K; k += BLOCK) {
    const float4* ep = (const float4*)(emb + (size_t)k * D);
    float4 s4 = {0.f, 0.f, 0.f, 0.f};
#pragma unroll
    for (int d = 0; d < 16; ++d) {
      float4 v = ep[d];
      s4.x = fmaf(v.x, v.x, s4.x);
      s4.y = fmaf(v.y, v.y, s4.y);
      s4.z = fmaf(v.z, v.z, s4.z);
      s4.w = fmaf(v.w, v.w, s4.w);
    }
    s_norm[k] = (s4.x + s4.y) + (s4.z + s4.w);
  }
  __syncthreads();

  const int lane = tid & 63;
  const int wid = tid >> 6;
  const int gw = blockIdx.x * WPB + wid;
  const int nw = gridDim.x * WPB;
  const int l15 = lane & 15;
  const int q = lane >> 4;

// load + hi/lo-split one 16-row A tile into named frag vars
#define LOADX(a)                                                   \
  do {                                                             \
    const float* xp_ = x + (size_t)(row0 + (a)*16 + l15) * D + q * 8; \
    float4 u0_ = *(const float4*)xp_;                              \
    float4 u1_ = *(const float4*)(xp_ + 4);                        \
    float4 w0_ = *(const float4*)(xp_ + 32);                       \
    float4 w1_ = *(const float4*)(xp_ + 36);                       \
    SPL(xh##a##0, xl##a##0, 0, u0_.x);                             \
    SPL(xh##a##0, xl##a##0, 1, u0_.y);                             \
    SPL(xh##a##0, xl##a##0, 2, u0_.z);                             \
    SPL(xh##a##0, xl##a##0, 3, u0_.w);                             \
    SPL(xh##a##0, xl##a##0, 4, u1_.x);                             \
    SPL(xh##a##0, xl##a##0, 5, u1_.y);                             \
    SPL(xh##a##0, xl##a##0, 6, u1_.z);                             \
    SPL(xh##a##0, xl##a##0, 7, u1_.w);                             \
    SPL(xh##a##1, xl##a##1, 0, w0_.x);                             \
    SPL(xh##a##1, xl##a##1, 1, w0_.y);                             \
    SPL(xh##a##1, xl##a##1, 2, w0_.z);                             \
    SPL(xh##a##1, xl##a##1, 3, w0_.w);                             \
    SPL(xh##a##1, xl##a##1, 4, w1_.x);                             \
    SPL(xh##a##1, xl##a##1, 5, w1_.y);                             \
    SPL(xh##a##1, xl##a##1, 6, w1_.z);                             \
    SPL(xh##a##1, xl##a##1, 7, w1_.w);                             \
  } while (0)

// one 16x16 output tile: 6 MFMAs + 4 selects, all state in named vectors
#define PROCA(a)                                                              \
  do {                                                                        \
    f32x4 ah_ = {nn, nn, nn, nn};                                             \
    f32x4 al_ = {0.f, 0.f, 0.f, 0.f};                                         \
    ah_ = __builtin_amdgcn_mfma_f32_16x16x32_f16(xh##a##0, b0, ah_, 0, 0, 0); \
    ah_ = __builtin_amdgcn_mfma_f32_16x16x32_f16(xh##a##1, b2, ah_, 0, 0, 0); \
    al_ = __builtin_amdgcn_mfma_f32_16x16x32_f16(xh##a##0, b1, al_, 0, 0, 0); \
    al_ = __builtin_amdgcn_mfma_f32_16x16x32_f16(xl##a##0, b0, al_, 0, 0, 0); \
    al_ = __builtin_amdgcn_mfma_f32_16x16x32_f16(xh##a##1, b3, al_, 0, 0, 0); \
    al_ = __builtin_amdgcn_mfma_f32_16x16x32_f16(xl##a##1, b2, al_, 0, 0, 0); \
    _Pragma("unroll") for (int i_ = 0; i_ < 4; ++i_) {                        \
      float m_ = fmaf(al_[i_], 4.8828125e-4f, ah_[i_]); /* incl -||e||^2 */   \
      bool gt_ = m_ > bm##a[i_];                                              \
      bm##a[i_] = gt_ ? m_ : bm##a[i_];                                       \
      bt##a[i_] = gt_ ? t : bt##a[i_];                                        \
    }                                                                         \
  } while (0)

// one argmin-reduce step for tile-row group a at xor-mask mm
#define RSTA(a, mm)                                                        \
  _Pragma("unroll") for (int i_ = 0; i_ < 4; ++i_) {                       \
    float ov_ = __shfl_xor(bm##a[i_], (mm), 64);                           \
    int ok_ = __shfl_xor(bk##a[i_], (mm), 64);                             \
    bool tk_ = (ov_ > bm##a[i_]) || ((ov_ == bm##a[i_]) && (ok_ < bk##a[i_])); \
    bm##a[i_] = tk_ ? ov_ : bm##a[i_];                                     \
    bk##a[i_] = tk_ ? ok_ : bk##a[i_];                                     \
  }

// gather + coalesced write of the 16 rows of group a
#define WRA(a)                                                \
  do {                                                        \
    int j_ = (lane >> 2) & 3;                                 \
    int k01_ = (j_ & 1) ? bk##a[1] : bk##a[0];                \
    int k23_ = (j_ & 1) ? bk##a[3] : bk##a[2];                \
    int kk_ = (j_ & 2) ? k23_ : k01_;                         \
    int r_ = row0 + (a)*16 + (lane >> 2);                     \
    const f32x4* src_ = (const f32x4*)(emb + (size_t)kk_ * D);\
    f32x4* dst_ = (f32x4*)(out + (size_t)r_ * D);             \
    _Pragma("unroll") for (int s_ = 0; s_ < 4; ++s_) {        \
      int idx_ = (lane & 3) + (s_ << 2);                      \
      dst_[idx_] = src_[idx_];                                \
    }                                                         \
  } while (0)

  const int ngrp = nrows >> 6; // 64 rows per wave-iteration
  for (int g = gw; g < ngrp; g += nw) {
    const int row0 = g << 6;

    f16x8 xh00, xh01, xl00, xl01;
    f16x8 xh10, xh11, xl10, xl11;
    f16x8 xh20, xh21, xl20, xl21;
    f16x8 xh30, xh31, xl30, xl31;
    LOADX(0);
    LOADX(1);
    LOADX(2);
    LOADX(3);

    f32x4 bm0, bm1, bm2, bm3;
    i32x4 bt0, bt1, bt2, bt3;
    bm0 = bm1 = bm2 = bm3 = (f32x4){-3.4e38f, -3.4e38f, -3.4e38f, -3.4e38f};
    bt0 = bt1 = bt2 = bt3 = (i32x4){0, 0, 0, 0};

    // ---- 25 code tiles: 4 ds_read_b128 feed 24 MFMAs ----
    for (int t = 0; t < KT; ++t) {
      f16x8 b0 = *(const f16x8*)&sB[t][0][lane][0];
      f16x8 b1 = *(const f16x8*)&sB[t][1][lane][0];
      f16x8 b2 = *(const f16x8*)&sB[t][2][lane][0];
      f16x8 b3 = *(const f16x8*)&sB[t][3][lane][0];
      float nn = -s_norm[t * 16 + l15];
      PROCA(0);
      PROCA(1);
      PROCA(2);
      PROCA(3);
    }

    // ---- argmin reduce across the 16 lanes of each row-group ----
    i32x4 bk0 = bt0 * 16 + l15;
    i32x4 bk1 = bt1 * 16 + l15;
    i32x4 bk2 = bt2 * 16 + l15;
    i32x4 bk3 = bt3 * 16 + l15;
#pragma unroll
    for (int mm = 1; mm <= 8; mm <<= 1) {
      RSTA(0, mm)
      RSTA(1, mm)
      RSTA(2, mm)
      RSTA(3, mm)
    }

    WRA(0);
    WRA(1);
    WRA(2);
    WRA(3);
  }
#undef LOADX
#undef PROCA
#undef RSTA
#undef WRA
}

extern "C" void kernel_launch(void* const* d_in, const int* in_sizes, int n_in,
                              void* d_out, int out_size, void* d_ws, size_t ws_size,
                              hipStream_t stream) {
  const float* x = (const float*)d_in[0];
  const float* emb = (const float*)d_in[1];
  float* out = (float*)d_out;
  int nrows = in_sizes[0] / D; // 262144
  vq_mfma<<<512, BLOCK, 0, stream>>>(x, emb, out, nrows);
}

// Round 6
// 154.324 us; speedup vs baseline: 1.1467x; 1.0527x over previous
//
#include <hip/hip_runtime.h>

#define D 64
#define K 400
#define KT 25            // K/16 code tiles
#define BLOCK 256
#define WPB (BLOCK / 64) // 4 waves per block
#define NRM_OFF 102400   // byte offset of norms in workspace

typedef _Float16 f16x8 __attribute__((ext_vector_type(8)));
typedef float f32x4 __attribute__((ext_vector_type(4)));
typedef int i32x4 __attribute__((ext_vector_type(4)));

// scores = ||e||^2 - 2 x.e ; computed via f16 hi/lo split MFMA:
//   2e = eh + 2^-11 el,  x = xh + 2^-11 xl   (el, xl stored pre-scaled by 2^11)
//   dot(x,2e) ~= [xh.eh] + 2^-11 [xh.el + xl.eh]
// argmax over (dot - ||e||^2)  ==  argmin over score.
//
// R6: NO LDS. R5 was "clean" (0 conflicts, ideal traffic, regs in place)
// yet 80% stall: the 104KB LDS codebook pinned 1 block/CU -> 2 waves/SIMD,
// plus per-block staging + syncthreads + one-shot compute. Here a prep
// kernel reorders the codebook ONCE into d_ws in fragment layout; the main
// kernel reads B-frags via coalesced global_load_dwordx4 (L2-resident,
// ~200cy, hidden by TLP). Occupancy becomes VGPR-bound (~4-5 waves/SIMD),
// no barriers, no staging. Zero-alloca discipline kept from R5.

__global__ void vq_prep(const float* __restrict__ emb, void* __restrict__ ws) {
  _Float16* B = (_Float16*)ws;                    // [25][4][64][8] f16
  float* nrm = (float*)((char*)ws + NRM_OFF);     // [400] f32
  int gid = blockIdx.x * blockDim.x + threadIdx.x;
  if (gid < KT * 4 * 64) {
    int t = gid >> 8;
    int f = (gid >> 6) & 3;
    int l = gid & 63;
    int code = t * 16 + (l & 15);
    int kb = ((l >> 4) << 3) + ((f >> 1) << 5);
    const float* ep = emb + code * D + kb;
    float4 u = *(const float4*)ep;
    float4 w = *(const float4*)(ep + 4);
    f16x8 h;
    if ((f & 1) == 0) {
      h[0] = (_Float16)(2.0f * u.x);
      h[1] = (_Float16)(2.0f * u.y);
      h[2] = (_Float16)(2.0f * u.z);
      h[3] = (_Float16)(2.0f * u.w);
      h[4] = (_Float16)(2.0f * w.x);
      h[5] = (_Float16)(2.0f * w.y);
      h[6] = (_Float16)(2.0f * w.z);
      h[7] = (_Float16)(2.0f * w.w);
    } else {
#define LOC(j, val)                                    \
      do {                                             \
        float s_ = 2.0f * (val);                       \
        _Float16 t_ = (_Float16)s_;                    \
        h[j] = (_Float16)((s_ - (float)t_) * 2048.0f); \
      } while (0)
      LOC(0, u.x); LOC(1, u.y); LOC(2, u.z); LOC(3, u.w);
      LOC(4, w.x); LOC(5, w.y); LOC(6, w.z); LOC(7, w.w);
#undef LOC
    }
    *(f16x8*)&B[gid * 8] = h;
  }
  if (gid < K) {
    const float4* ep = (const float4*)(emb + (size_t)gid * D);
    float4 s4 = {0.f, 0.f, 0.f, 0.f};
#pragma unroll
    for (int d = 0; d < 16; ++d) {
      float4 v = ep[d];
      s4.x = fmaf(v.x, v.x, s4.x);
      s4.y = fmaf(v.y, v.y, s4.y);
      s4.z = fmaf(v.z, v.z, s4.z);
      s4.w = fmaf(v.w, v.w, s4.w);
    }
    nrm[gid] = (s4.x + s4.y) + (s4.z + s4.w);
  }
}

#define SPL(hh, ll, j, val)                          \
  do {                                               \
    float v_ = (val);                                \
    _Float16 t_ = (_Float16)v_;                      \
    (hh)[j] = t_;                                    \
    (ll)[j] = (_Float16)((v_ - (float)t_) * 2048.0f);\
  } while (0)

__global__ __launch_bounds__(BLOCK) void vq_mfma(
    const float* __restrict__ x,
    const float* __restrict__ emb,
    const void* __restrict__ ws,
    float* __restrict__ out,
    int nrows) {
  const f16x8* B = (const f16x8*)ws;                       // [25*4*64]
  const float* nrm = (const float*)((const char*)ws + NRM_OFF);

  const int tid = threadIdx.x;
  const int lane = tid & 63;
  const int wid = tid >> 6;
  const int gw = blockIdx.x * WPB + wid;
  const int nw = gridDim.x * WPB;
  const int l15 = lane & 15;
  const int q = lane >> 4;

// load + hi/lo-split one 16-row A tile into named frag vars
#define LOADX(a)                                                   \
  do {                                                             \
    const float* xp_ = x + (size_t)(row0 + (a)*16 + l15) * D + q * 8; \
    float4 u0_ = *(const float4*)xp_;                              \
    float4 u1_ = *(const float4*)(xp_ + 4);                        \
    float4 w0_ = *(const float4*)(xp_ + 32);                       \
    float4 w1_ = *(const float4*)(xp_ + 36);                       \
    SPL(xh##a##0, xl##a##0, 0, u0_.x);                             \
    SPL(xh##a##0, xl##a##0, 1, u0_.y);                             \
    SPL(xh##a##0, xl##a##0, 2, u0_.z);                             \
    SPL(xh##a##0, xl##a##0, 3, u0_.w);                             \
    SPL(xh##a##0, xl##a##0, 4, u1_.x);                             \
    SPL(xh##a##0, xl##a##0, 5, u1_.y);                             \
    SPL(xh##a##0, xl##a##0, 6, u1_.z);                             \
    SPL(xh##a##0, xl##a##0, 7, u1_.w);                             \
    SPL(xh##a##1, xl##a##1, 0, w0_.x);                             \
    SPL(xh##a##1, xl##a##1, 1, w0_.y);                             \
    SPL(xh##a##1, xl##a##1, 2, w0_.z);                             \
    SPL(xh##a##1, xl##a##1, 3, w0_.w);                             \
    SPL(xh##a##1, xl##a##1, 4, w1_.x);                             \
    SPL(xh##a##1, xl##a##1, 5, w1_.y);                             \
    SPL(xh##a##1, xl##a##1, 6, w1_.z);                             \
    SPL(xh##a##1, xl##a##1, 7, w1_.w);                             \
  } while (0)

// one 16x16 output tile: 6 MFMAs + 4 selects, all state in named vectors
#define PROCA(a)                                                              \
  do {                                                                        \
    f32x4 ah_ = {nn, nn, nn, nn};                                             \
    f32x4 al_ = {0.f, 0.f, 0.f, 0.f};                                         \
    ah_ = __builtin_amdgcn_mfma_f32_16x16x32_f16(xh##a##0, b0, ah_, 0, 0, 0); \
    ah_ = __builtin_amdgcn_mfma_f32_16x16x32_f16(xh##a##1, b2, ah_, 0, 0, 0); \
    al_ = __builtin_amdgcn_mfma_f32_16x16x32_f16(xh##a##0, b1, al_, 0, 0, 0); \
    al_ = __builtin_amdgcn_mfma_f32_16x16x32_f16(xl##a##0, b0, al_, 0, 0, 0); \
    al_ = __builtin_amdgcn_mfma_f32_16x16x32_f16(xh##a##1, b3, al_, 0, 0, 0); \
    al_ = __builtin_amdgcn_mfma_f32_16x16x32_f16(xl##a##1, b2, al_, 0, 0, 0); \
    _Pragma("unroll") for (int i_ = 0; i_ < 4; ++i_) {                        \
      float m_ = fmaf(al_[i_], 4.8828125e-4f, ah_[i_]); /* incl -||e||^2 */   \
      bool gt_ = m_ > bm##a[i_];                                              \
      bm##a[i_] = gt_ ? m_ : bm##a[i_];                                       \
      bt##a[i_] = gt_ ? t : bt##a[i_];                                        \
    }                                                                         \
  } while (0)

// one argmin-reduce step for tile-row group a at xor-mask mm
#define RSTA(a, mm)                                                        \
  _Pragma("unroll") for (int i_ = 0; i_ < 4; ++i_) {                       \
    float ov_ = __shfl_xor(bm##a[i_], (mm), 64);                           \
    int ok_ = __shfl_xor(bk##a[i_], (mm), 64);                             \
    bool tk_ = (ov_ > bm##a[i_]) || ((ov_ == bm##a[i_]) && (ok_ < bk##a[i_])); \
    bm##a[i_] = tk_ ? ov_ : bm##a[i_];                                     \
    bk##a[i_] = tk_ ? ok_ : bk##a[i_];                                     \
  }

// gather + coalesced write of the 16 rows of group a
#define WRA(a)                                                \
  do {                                                        \
    int j_ = (lane >> 2) & 3;                                 \
    int k01_ = (j_ & 1) ? bk##a[1] : bk##a[0];                \
    int k23_ = (j_ & 1) ? bk##a[3] : bk##a[2];                \
    int kk_ = (j_ & 2) ? k23_ : k01_;                         \
    int r_ = row0 + (a)*16 + (lane >> 2);                     \
    const f32x4* src_ = (const f32x4*)(emb + (size_t)kk_ * D);\
    f32x4* dst_ = (f32x4*)(out + (size_t)r_ * D);             \
    _Pragma("unroll") for (int s_ = 0; s_ < 4; ++s_) {        \
      int idx_ = (lane & 3) + (s_ << 2);                      \
      dst_[idx_] = src_[idx_];                                \
    }                                                         \
  } while (0)

  const int ngrp = nrows >> 6; // 64 rows per wave-iteration
  for (int g = gw; g < ngrp; g += nw) {
    const int row0 = g << 6;

    f16x8 xh00, xh01, xl00, xl01;
    f16x8 xh10, xh11, xl10, xl11;
    f16x8 xh20, xh21, xl20, xl21;
    f16x8 xh30, xh31, xl30, xl31;
    LOADX(0);
    LOADX(1);
    LOADX(2);
    LOADX(3);

    f32x4 bm0, bm1, bm2, bm3;
    i32x4 bt0, bt1, bt2, bt3;
    bm0 = bm1 = bm2 = bm3 = (f32x4){-3.4e38f, -3.4e38f, -3.4e38f, -3.4e38f};
    bt0 = bt1 = bt2 = bt3 = (i32x4){0, 0, 0, 0};

    // ---- 25 code tiles: 4 coalesced global (L2-hot) loads feed 24 MFMAs ----
    for (int t = 0; t < KT; ++t) {
      f16x8 b0 = B[(t * 4 + 0) * 64 + lane];
      f16x8 b1 = B[(t * 4 + 1) * 64 + lane];
      f16x8 b2 = B[(t * 4 + 2) * 64 + lane];
      f16x8 b3 = B[(t * 4 + 3) * 64 + lane];
      float nn = -nrm[t * 16 + l15];
      PROCA(0);
      PROCA(1);
      PROCA(2);
      PROCA(3);
    }

    // ---- argmin reduce across the 16 lanes of each row-group ----
    i32x4 bk0 = bt0 * 16 + l15;
    i32x4 bk1 = bt1 * 16 + l15;
    i32x4 bk2 = bt2 * 16 + l15;
    i32x4 bk3 = bt3 * 16 + l15;
#pragma unroll
    for (int mm = 1; mm <= 8; mm <<= 1) {
      RSTA(0, mm)
      RSTA(1, mm)
      RSTA(2, mm)
      RSTA(3, mm)
    }

    WRA(0);
    WRA(1);
    WRA(2);
    WRA(3);
  }
#undef LOADX
#undef PROCA
#undef RSTA
#undef WRA
}

extern "C" void kernel_launch(void* const* d_in, const int* in_sizes, int n_in,
                              void* d_out, int out_size, void* d_ws, size_t ws_size,
                              hipStream_t stream) {
  const float* x = (const float*)d_in[0];
  const float* emb = (const float*)d_in[1];
  float* out = (float*)d_out;
  int nrows = in_sizes[0] / D; // 262144
  vq_prep<<<25, 256, 0, stream>>>(emb, d_ws);
  vq_mfma<<<1024, BLOCK, 0, stream>>>(x, emb, d_ws, out, nrows);
}